// Round 2
// baseline (169.309 us; speedup 1.0000x reference)
//
#include <hip/hip_runtime.h>
#include <hip/hip_bf16.h>

// SimpleTransformer: qkv = x @ W^T + b ; banded causal attention (window 129).
// B=4, T=4096, D=512, HISTORY=128. Inputs fp32, output fp32 (per reference).
// Internally: convert x,W to bf16 once, MFMA-bf16 GEMM + attention, fp32 out.
#define T_SEQ 4096
#define D_DIM 512
#define NBATCH 4
#define HIST 128

typedef short short8 __attribute__((ext_vector_type(8)));   // 8 x bf16 bits (4 VGPRs)
typedef float f32x4 __attribute__((ext_vector_type(4)));

static __device__ __forceinline__ f32x4 mfma_bf16(short8 a, short8 b, f32x4 c) {
  return __builtin_amdgcn_mfma_f32_16x16x32_bf16(a, b, c, 0, 0, 0);
}

static __device__ __forceinline__ ushort f2bf_bits(float f) {
  __hip_bfloat16 h = __float2bfloat16(f);
  return *reinterpret_cast<ushort*>(&h);
}

// ---------------------------------------------------------------------------
// Kernel 0: fp32 -> bf16 conversion of x (8388608) and W (786432), 8 elems/thread.
// ---------------------------------------------------------------------------
__global__ __launch_bounds__(256)
void cvt_kernel(const float* __restrict__ X, const float* __restrict__ W,
                ushort* __restrict__ Xb, ushort* __restrict__ Wb) {
  constexpr size_t NX = (size_t)NBATCH * T_SEQ * D_DIM;   // 8388608
  const size_t off = ((size_t)blockIdx.x * 256 + threadIdx.x) * 8;
  const float* s;
  ushort* d;
  if (off < NX) { s = X + off; d = Xb + off; }
  else          { s = W + (off - NX); d = Wb + (off - NX); }
  const float4 a = *(const float4*)s;
  const float4 b = *(const float4*)(s + 4);
  short8 v;
  v[0] = f2bf_bits(a.x); v[1] = f2bf_bits(a.y);
  v[2] = f2bf_bits(a.z); v[3] = f2bf_bits(a.w);
  v[4] = f2bf_bits(b.x); v[5] = f2bf_bits(b.y);
  v[6] = f2bf_bits(b.z); v[7] = f2bf_bits(b.w);
  *(short8*)d = v;
}

// ---------------------------------------------------------------------------
// Kernel 1: qkv[m][n] = sum_k X[m][k] * W[n][k] + bias[n]   (bf16 in, fp32 acc)
//   M = 16384, N = 1536, K = 512. Tile 128x128, BK=64, 256 threads (2x2 waves).
//   LDS: 16B chunk (m,kq) at chunk index m*8 + (kq ^ (m&7)) — conflict-free
//   for both staging writes and ds_read_b128 fragment reads.
//   Epilogue: n in [0,512)->Q, [512,1024)->K (row-major bf16),
//             [1024,1536)->V stored transposed as Vt[b][d][t] bf16.
// ---------------------------------------------------------------------------
__global__ __launch_bounds__(256, 2)
void qkv_gemm_kernel(const ushort* __restrict__ X,
                     const ushort* __restrict__ W,
                     const float* __restrict__ bias,
                     ushort* __restrict__ Qo,
                     ushort* __restrict__ Ko,
                     ushort* __restrict__ Vt) {
  constexpr int BK = 64, KD = D_DIM;
  __shared__ ushort sA[128 * BK];   // 16 KB
  __shared__ ushort sB[128 * BK];   // 16 KB

  const int tid  = threadIdx.x;
  const int wave = tid >> 6, lane = tid & 63;
  const int col  = lane & 15, quad = lane >> 4;
  const int m0 = blockIdx.x * 128;
  const int n0 = blockIdx.y * 128;
  const int wm = (wave >> 1) * 64, wn = (wave & 1) * 64;

  f32x4 acc[4][4];
#pragma unroll
  for (int i = 0; i < 4; ++i)
#pragma unroll
    for (int j = 0; j < 4; ++j) acc[i][j] = (f32x4)0.0f;

  for (int k0 = 0; k0 < KD; k0 += BK) {
    __syncthreads();
#pragma unroll
    for (int j = 0; j < 4; ++j) {
      const int c  = j * 256 + tid;          // 1024 16B-chunks per tile
      const int m  = c >> 3;
      const int kq = c & 7;
      const int sw = (m * 8 + (kq ^ (m & 7))) * 8;
      *(int4*)(&sA[sw]) = *(const int4*)(X + (size_t)(m0 + m) * KD + k0 + kq * 8);
      *(int4*)(&sB[sw]) = *(const int4*)(W + (size_t)(n0 + m) * KD + k0 + kq * 8);
    }
    __syncthreads();
#pragma unroll
    for (int ks = 0; ks < 2; ++ks) {
      const int kq = ks * 4 + quad;
      short8 af[4], bf[4];
#pragma unroll
      for (int mt = 0; mt < 4; ++mt) {
        const int m = wm + mt * 16 + col;
        af[mt] = *(const short8*)(&sA[(m * 8 + (kq ^ (m & 7))) * 8]);
      }
#pragma unroll
      for (int nt = 0; nt < 4; ++nt) {
        const int n = wn + nt * 16 + col;
        bf[nt] = *(const short8*)(&sB[(n * 8 + (kq ^ (n & 7))) * 8]);
      }
#pragma unroll
      for (int mt = 0; mt < 4; ++mt)
#pragma unroll
        for (int nt = 0; nt < 4; ++nt)
          acc[mt][nt] = mfma_bf16(af[mt], bf[nt], acc[mt][nt]);
    }
  }

  const int region = n0 >> 9;   // 0=Q, 1=K, 2=V (tiles never straddle)
#pragma unroll
  for (int nt = 0; nt < 4; ++nt) {
    const int ng = n0 + wn + nt * 16 + col;
    const float bv = bias[ng];
    const int d = ng & (D_DIM - 1);
#pragma unroll
    for (int mt = 0; mt < 4; ++mt) {
      const int mg = m0 + wm + mt * 16 + quad * 4;   // C/D: row = quad*4 + r
#pragma unroll
      for (int r = 0; r < 4; ++r) {
        const ushort hv = f2bf_bits(acc[mt][nt][r] + bv);
        const int mr = mg + r;
        if (region == 0) {
          Qo[(size_t)mr * D_DIM + d] = hv;
        } else if (region == 1) {
          Ko[(size_t)mr * D_DIM + d] = hv;
        } else {
          const int bb = mr >> 12;
          const int tt = mr & (T_SEQ - 1);
          Vt[((size_t)bb * D_DIM + d) * T_SEQ + tt] = hv;
        }
      }
    }
  }
}

// ---------------------------------------------------------------------------
// Kernel 2: banded attention. One block per (batch, 64-query tile).
//   Key span [t0-128, t0+64) = 192 keys = 4 waves * 48 columns.
//   S = Q K^T * scale via MFMA from global (L2-hot); banded softmax in LDS;
//   O = P V via MFMA (P bf16 LDS A-frags, V^T global B-frags); fp32 out.
// ---------------------------------------------------------------------------
__global__ __launch_bounds__(256)
void attn_kernel(const ushort* __restrict__ Qb,
                 const ushort* __restrict__ Kb,
                 const ushort* __restrict__ Vtb,
                 float* __restrict__ out) {
  constexpr int SLD = 193;   // fp32 stride (odd) -> conflict-free softmax sweeps
  constexpr int PLD = 200;   // bf16 stride, 400B rows (16B aligned)
  __shared__ float  S[64 * SLD];   // 49408 B
  __shared__ ushort P[64 * PLD];   // 25600 B

  const int tid  = threadIdx.x;
  const int wave = tid >> 6, lane = tid & 63;
  const int col  = lane & 15, quad = lane >> 4;
  const int b  = blockIdx.x >> 6;
  const int t0 = (blockIdx.x & 63) * 64;
  const int s0 = t0 - HIST;

  const ushort* Qp = Qb  + (size_t)b * T_SEQ * D_DIM;
  const ushort* Kp = Kb  + (size_t)b * T_SEQ * D_DIM;
  const ushort* Vp = Vtb + (size_t)b * D_DIM * T_SEQ;

  // ---- phase 1: S[64][192] = Q K^T ----
  f32x4 sacc[4][3];
#pragma unroll
  for (int i = 0; i < 4; ++i)
#pragma unroll
    for (int j = 0; j < 3; ++j) sacc[i][j] = (f32x4)0.0f;

#pragma unroll 2
  for (int ks = 0; ks < 16; ++ks) {        // K = 512 = 16 * 32
    const int kk = ks * 32 + quad * 8;
    short8 af[4];
#pragma unroll
    for (int mt = 0; mt < 4; ++mt)
      af[mt] = *(const short8*)(Qp + (size_t)(t0 + mt * 16 + col) * D_DIM + kk);
#pragma unroll
    for (int st = 0; st < 3; ++st) {
      int sg = s0 + wave * 48 + st * 16 + col;
      sg = sg < 0 ? 0 : sg;                // clamped keys masked in softmax
      const short8 bfr = *(const short8*)(Kp + (size_t)sg * D_DIM + kk);
#pragma unroll
      for (int mt = 0; mt < 4; ++mt)
        sacc[mt][st] = mfma_bf16(af[mt], bfr, sacc[mt][st]);
    }
  }
  const float scale = 0.04419417382415922f;   // 1/sqrt(512)
#pragma unroll
  for (int mt = 0; mt < 4; ++mt)
#pragma unroll
    for (int st = 0; st < 3; ++st) {
      const int row = mt * 16 + quad * 4;
      const int c   = wave * 48 + st * 16 + col;
#pragma unroll
      for (int r = 0; r < 4; ++r)
        S[(row + r) * SLD + c] = sacc[mt][st][r] * scale;
    }
  __syncthreads();

  // ---- banded softmax: 4 threads per row, 48 cols each ----
  {
    const int row  = tid >> 2, part = tid & 3;
    const int lo = max(row, HIST - t0);   // j_local >= row and key >= 0
    const int hi = row + HIST;            // causal end (<= 191)
    float* Srow = S + row * SLD;
    const int j0 = part * 48;
    float mx = -3.0e38f;
    for (int j = j0; j < j0 + 48; ++j)
      if (j >= lo && j <= hi) mx = fmaxf(mx, Srow[j]);
    mx = fmaxf(mx, __shfl_xor(mx, 1));
    mx = fmaxf(mx, __shfl_xor(mx, 2));
    float sum = 0.f;
    for (int j = j0; j < j0 + 48; ++j) {
      if (j >= lo && j <= hi) {
        const float e = __expf(Srow[j] - mx);
        Srow[j] = e;
        sum += e;
      }
    }
    sum += __shfl_xor(sum, 1);
    sum += __shfl_xor(sum, 2);
    const float inv = 1.0f / sum;
    ushort* Prow = P + row * PLD;
    for (int j = j0; j < j0 + 48; ++j) {
      const float v = (j >= lo && j <= hi) ? Srow[j] * inv : 0.0f;
      Prow[j] = f2bf_bits(v);
    }
  }
  __syncthreads();

  // ---- phase 2: O[64][512] = P[64][192] @ V[192][512] ----
#pragma unroll 2
  for (int nt = 0; nt < 8; ++nt) {
    const int d = wave * 128 + nt * 16 + col;
    f32x4 oacc[4];
#pragma unroll
    for (int i = 0; i < 4; ++i) oacc[i] = (f32x4)0.0f;
#pragma unroll
    for (int ksv = 0; ksv < 6; ++ksv) {    // 192 = 6 * 32
      int sg = s0 + ksv * 32 + quad * 8;
      sg = sg < 0 ? 0 : sg;                // P is 0 there
      const short8 bfr = *(const short8*)(Vp + (size_t)d * T_SEQ + sg);
#pragma unroll
      for (int mt = 0; mt < 4; ++mt) {
        const short8 af = *(const short8*)(&P[(mt * 16 + col) * PLD + ksv * 32 + quad * 8]);
        oacc[mt] = mfma_bf16(af, bfr, oacc[mt]);
      }
    }
#pragma unroll
    for (int mt = 0; mt < 4; ++mt) {
      const int mg = t0 + mt * 16 + quad * 4;
#pragma unroll
      for (int r = 0; r < 4; ++r)
        out[((size_t)b * T_SEQ + mg + r) * D_DIM + d] = oacc[mt][r];
    }
  }
}

// ---------------------------------------------------------------------------
extern "C" void kernel_launch(void* const* d_in, const int* in_sizes, int n_in,
                              void* d_out, int out_size, void* d_ws, size_t ws_size,
                              hipStream_t stream) {
  const float* X    = (const float*)d_in[0];   // (B*T, 512) fp32
  const float* W    = (const float*)d_in[1];   // (1536, 512) fp32
  const float* bias = (const float*)d_in[2];   // (1536,) fp32

  // ws layout (bf16/ushort): Xb | Wb | Q | K | Vt   (~68.7 MB total)
  const size_t NX = (size_t)NBATCH * T_SEQ * D_DIM;   // 8388608
  const size_t NW = (size_t)3 * D_DIM * D_DIM;        // 786432
  ushort* Xb = (ushort*)d_ws;
  ushort* Wb = Xb + NX;
  ushort* Qw = Wb + NW;
  ushort* Kw = Qw + NX;
  ushort* Vw = Kw + NX;

  {
    const int nchunks = (int)((NX + NW) / 8);          // 1146880
    cvt_kernel<<<nchunks / 256, 256, 0, stream>>>(X, W, Xb, Wb);
  }

  dim3 g1(128, 12), b1(256);   // M/128 = 128, N/128 = 12
  qkv_gemm_kernel<<<g1, b1, 0, stream>>>(Xb, Wb, bias, Qw, Kw, Vw);

  dim3 g2(NBATCH * (T_SEQ / 64)), b2(256);
  attn_kernel<<<g2, b2, 0, stream>>>(Qw, Kw, Vw, (float*)d_out);
}